// Round 1
// baseline (6250.953 us; speedup 1.0000x reference)
//
#include <hip/hip_runtime.h>

#define TT 2048
#define BB 256
#define HID 64

__device__ __forceinline__ float frcp(float x) { return __builtin_amdgcn_rcpf(x); }
__device__ __forceinline__ float fsig(float x) { return frcp(1.f + __expf(-x)); }
// tanh(x) = 1 - 2/(1+e^{2x}) : stable at +/-inf (no inf-inf)
__device__ __forceinline__ float ftanh(float x) { return 1.f - 2.f * frcp(1.f + __expf(2.f * x)); }

// Raw workgroup barrier: waits LDS ops only (lgkmcnt), does NOT drain vmcnt —
// global prefetch loads / h-stores stay in flight across the barrier.
__device__ __forceinline__ void wg_barrier_lds() {
    asm volatile("s_waitcnt lgkmcnt(0)" ::: "memory");
    __builtin_amdgcn_s_barrier();
    asm volatile("" ::: "memory");
}

// pre = in(R,K) @ W(256,K)^T + b_ih + b_hh  -> out(R,256)
// block: 256 threads, tile 64 rows x 256 cols, k-chunks of 16.  (unchanged, proven)
__global__ __launch_bounds__(256, 2) void gemm_pre_k(
    const float* __restrict__ in, const float* __restrict__ W,
    const float* __restrict__ b_ih, const float* __restrict__ b_hh,
    float* __restrict__ out, int K)
{
    __shared__ __align__(16) float in_s[64][20];   // +4 pad keeps float4 align, breaks conflicts
    __shared__ __align__(16) float w_s[16][256];   // transposed W chunk: w_s[k][g]

    const int tid = threadIdx.x;
    const int tx = tid & 15, ty = tid >> 4;
    const long long row0 = (long long)blockIdx.x * 64;

    float4 bias[4];
    {
        const float4* bi4 = (const float4*)b_ih;
        const float4* bh4 = (const float4*)b_hh;
#pragma unroll
        for (int jj = 0; jj < 4; ++jj) {
            float4 a = bi4[tx * 4 + jj], b = bh4[tx * 4 + jj];
            bias[jj] = make_float4(a.x + b.x, a.y + b.y, a.z + b.z, a.w + b.w);
        }
    }

    float4 acc[4][4];
#pragma unroll
    for (int i = 0; i < 4; ++i)
#pragma unroll
        for (int j = 0; j < 4; ++j) acc[i][j] = make_float4(0.f, 0.f, 0.f, 0.f);

    const int rs = tid >> 2;   // 0..63 staging row
    const int kq = tid & 3;    // 0..3 staging k-quarter

    for (int kc = 0; kc < K; kc += 16) {
        __syncthreads();
        float4 iv = *(const float4*)(in + (row0 + rs) * K + kc + kq * 4);
        *(float4*)(&in_s[rs][kq * 4]) = iv;
        const float* wr = W + (long long)tid * K + kc;
        float4 w0 = ((const float4*)wr)[0];
        float4 w1 = ((const float4*)wr)[1];
        float4 w2 = ((const float4*)wr)[2];
        float4 w3 = ((const float4*)wr)[3];
        w_s[0][tid] = w0.x;  w_s[1][tid] = w0.y;  w_s[2][tid] = w0.z;  w_s[3][tid] = w0.w;
        w_s[4][tid] = w1.x;  w_s[5][tid] = w1.y;  w_s[6][tid] = w1.z;  w_s[7][tid] = w1.w;
        w_s[8][tid] = w2.x;  w_s[9][tid] = w2.y;  w_s[10][tid] = w2.z; w_s[11][tid] = w2.w;
        w_s[12][tid] = w3.x; w_s[13][tid] = w3.y; w_s[14][tid] = w3.z; w_s[15][tid] = w3.w;
        __syncthreads();

#pragma unroll
        for (int k2 = 0; k2 < 4; ++k2) {
            float4 a[4];
#pragma unroll
            for (int i = 0; i < 4; ++i) a[i] = *(const float4*)(&in_s[ty * 4 + i][k2 * 4]);
#pragma unroll
            for (int kk = 0; kk < 4; ++kk) {
                const int k = k2 * 4 + kk;
                float4 wv[4];
#pragma unroll
                for (int jj = 0; jj < 4; ++jj) wv[jj] = *(const float4*)(&w_s[k][tx * 16 + jj * 4]);
#pragma unroll
                for (int i = 0; i < 4; ++i) {
                    const float av = ((const float*)&a[i])[kk];
#pragma unroll
                    for (int jj = 0; jj < 4; ++jj) {
                        acc[i][jj].x += av * wv[jj].x;
                        acc[i][jj].y += av * wv[jj].y;
                        acc[i][jj].z += av * wv[jj].z;
                        acc[i][jj].w += av * wv[jj].w;
                    }
                }
            }
        }
    }

#pragma unroll
    for (int i = 0; i < 4; ++i) {
        float4* op = (float4*)(out + (row0 + ty * 4 + i) * 256 + tx * 16);
#pragma unroll
        for (int jj = 0; jj < 4; ++jj) {
            float4 v = acc[i][jj];
            v.x += bias[jj].x; v.y += bias[jj].y; v.z += bias[jj].z; v.w += bias[jj].w;
            op[jj] = v;
        }
    }
}

// Recurrent kernel, restructured:
//  - one block per batch element, 256 threads; thread tid owns gate g=tid.
//  - wave w = tid>>6 handles gates [64w,64w+64) -> per-wave uniform activation.
//  - ONE raw barrier per step (lgkm-only): gates exchanged via double-buffered
//    gbuf[2][256]; every wave redundantly computes the c/h update (identical fp
//    ops on identical inputs -> identical state) and broadcasts h through its
//    OWN h_s copy (within-wave DS ordering, no second barrier).
//  - pre[] prefetched 3 steps deep; loads/stores never drained at the barrier.
__global__ __launch_bounds__(256, 1) void lstm_rec_k(
    const float* __restrict__ pre, const float* __restrict__ w_hh,
    float* __restrict__ h_out)
{
    __shared__ __align__(16) float h_s[4][HID];   // per-wave private h copy
    __shared__ float gbuf[2][256];                // double-buffered gate exchange

    const int tid = threadIdx.x;
    const int w = tid >> 6;      // wave id 0..3
    const int j = tid & 63;      // lane id = h index
    const int b = blockIdx.x;

    // W_hh row for this gate in registers (64 VGPR)
    float4 w4[16];
    {
        const float4* wr = (const float4*)(w_hh + tid * HID);
#pragma unroll
        for (int k = 0; k < 16; ++k) w4[k] = wr[k];
    }

    float c = 0.f;
    float4 hv[16];               // h_{t-1} replicated per lane
#pragma unroll
    for (int k = 0; k < 16; ++k) hv[k] = make_float4(0.f, 0.f, 0.f, 0.f);

    // 3-deep register prefetch of pre[b][t][g]
    const float* pp = pre + (long long)b * TT * 256 + tid;
    float p0 = pp[0];
    float p1 = pp[256];
    float p2 = pp[512];
    pp += 768;                   // now points at t=3

    float* hop = h_out + (long long)b * TT * HID + j;

    for (int t = 0; t < TT; ++t) {
        // ---- phase A: gate_g = act(p_t + W_g . h_{t-1}) ----
        float s0 = 0.f, s1 = 0.f, s2 = 0.f, s3 = 0.f;
#pragma unroll
        for (int k = 0; k < 16; ++k) {
            s0 += w4[k].x * hv[k].x;
            s1 += w4[k].y * hv[k].y;
            s2 += w4[k].z * hv[k].z;
            s3 += w4[k].w * hv[k].w;
        }
        float acc = p0 + ((s0 + s1) + (s2 + s3));
        p0 = p1; p1 = p2;
        if (t + 3 < TT) p2 = pp[0];     // wave-uniform branch; stays in flight
        pp += 256;

        // gates [128,192) = cell gate (tanh) -> wave 2; others sigmoid
        float a = (w == 2) ? ftanh(acc) : fsig(acc);
        gbuf[t & 1][tid] = a;

        wg_barrier_lds();

        // ---- phase B: every wave updates (c,h) redundantly ----
        float iv = gbuf[t & 1][j];
        float fv = gbuf[t & 1][64 + j];
        float gv = gbuf[t & 1][128 + j];
        float ov = gbuf[t & 1][192 + j];
        c = fv * c + iv * gv;
        float h = ov * ftanh(c);
        if (w == 0) hop[(long long)t * HID] = h;   // fire-and-forget store

        h_s[w][j] = h;
        asm volatile("s_waitcnt lgkmcnt(0)" ::: "memory");  // own-wave write visible
        const float4* h4 = (const float4*)h_s[w];
#pragma unroll
        for (int k = 0; k < 16; ++k) hv[k] = h4[k];         // broadcast reads
    }
}

// out(r) = h(r,:) . fc_w + fc_b   — trivial GEMV epilogue, off the critical path
__global__ __launch_bounds__(256) void fc_k(
    const float* __restrict__ h, const float* __restrict__ fc_w,
    const float* __restrict__ fc_b, float* __restrict__ out, long long R)
{
    __shared__ __align__(16) float w_s[HID];
    if (threadIdx.x < HID) w_s[threadIdx.x] = fc_w[threadIdx.x];
    __syncthreads();

    long long r = (long long)blockIdx.x * 256 + threadIdx.x;
    if (r >= R) return;

    const float4* hp = (const float4*)(h + r * HID);
    const float4* wp = (const float4*)w_s;
    float s0 = 0.f, s1 = 0.f, s2 = 0.f, s3 = 0.f;
#pragma unroll
    for (int k = 0; k < 16; ++k) {
        float4 hv = hp[k];
        float4 wv = wp[k];       // wave-uniform LDS broadcast
        s0 += hv.x * wv.x;
        s1 += hv.y * wv.y;
        s2 += hv.z * wv.z;
        s3 += hv.w * wv.w;
    }
    out[r] = (s0 + s1) + (s2 + s3) + fc_b[0];
}

extern "C" void kernel_launch(void* const* d_in, const int* in_sizes, int n_in,
                              void* d_out, int out_size, void* d_ws, size_t ws_size,
                              hipStream_t stream)
{
    const float* x    = (const float*)d_in[0];
    const float* wih0 = (const float*)d_in[1];
    const float* whh0 = (const float*)d_in[2];
    const float* bih0 = (const float*)d_in[3];
    const float* bhh0 = (const float*)d_in[4];
    const float* wih1 = (const float*)d_in[5];
    const float* whh1 = (const float*)d_in[6];
    const float* bih1 = (const float*)d_in[7];
    const float* bhh1 = (const float*)d_in[8];
    const float* wih2 = (const float*)d_in[9];
    const float* whh2 = (const float*)d_in[10];
    const float* bih2 = (const float*)d_in[11];
    const float* bhh2 = (const float*)d_in[12];
    const float* fcw  = (const float*)d_in[13];
    const float* fcb  = (const float*)d_in[14];
    float* outp = (float*)d_out;

    const long long R = (long long)BB * TT;      // 524288 rows
    float* pre  = (float*)d_ws;                  // R*256 fp32 = 512 MB
    float* hbuf = pre + R * 256;                 // R*64  fp32 = 128 MB

    const int gemm_grid = (int)(R / 64);         // 8192

    // layer 0
    gemm_pre_k<<<gemm_grid, 256, 0, stream>>>(x, wih0, bih0, bhh0, pre, 128);
    lstm_rec_k<<<BB, 256, 0, stream>>>(pre, whh0, hbuf);
    // layer 1
    gemm_pre_k<<<gemm_grid, 256, 0, stream>>>(hbuf, wih1, bih1, bhh1, pre, 64);
    lstm_rec_k<<<BB, 256, 0, stream>>>(pre, whh1, hbuf);
    // layer 2
    gemm_pre_k<<<gemm_grid, 256, 0, stream>>>(hbuf, wih2, bih2, bhh2, pre, 64);
    lstm_rec_k<<<BB, 256, 0, stream>>>(pre, whh2, hbuf);
    // FC epilogue
    fc_k<<<(int)(R / 256), 256, 0, stream>>>(hbuf, fcw, fcb, outp, R);
}